// Round 15
// baseline (160.905 us; speedup 1.0000x reference)
//
#include <hip/hip_runtime.h>
#include <hip/hip_bf16.h>

typedef __attribute__((ext_vector_type(8)))  float f8;
typedef __attribute__((ext_vector_type(16))) float f32x16;
typedef __attribute__((ext_vector_type(8)))  short bf8;

__device__ __forceinline__ short f2bf(float f) {
    unsigned u = __builtin_bit_cast(unsigned, f);
    u += 0x7fff + ((u >> 16) & 1);          // round-to-nearest-even
    return (short)(u >> 16);
}

__device__ __forceinline__ unsigned cvt_pk_bf16(float a, float b) {
    unsigned r;
    asm("v_cvt_pk_bf16_f32 %0, %1, %2" : "=v"(r) : "v"(a), "v"(b));
    return r;                                // lo = bf16(a), hi = bf16(b)
}

// ---------------------------------------------------------------------------
// Prep (validated rounds 7/11-14, absmax 0.5): fused B-matrix [256][128]
// packed as 32x32x16 MFMA B-fragments. f = kt*4+nt, kt=0..15, nt=0..3:
//   pre[(f*64 + lane)*8 + j] = Bmat[kt*16 + (lane>>5)*8 + j][nt*32 + (lane&31)]
//   Bmat[k][n] = k<128 ? U_w[n][k]
//                      : A_w[n][k-128]*dw[k-128]/dw[n] + (n==k-128)*(0.05-rs[n])
// ---------------------------------------------------------------------------
__global__ void nemon_prep(const float* __restrict__ Uw,
                           const float* __restrict__ Aw,
                           const float* __restrict__ dvec,
                           short* __restrict__ pre)
{
    __shared__ float rs[128], dwv[128];
    const int tid = threadIdx.x;
    if (tid < 128) {
        float s = 0.f;
        #pragma unroll 8
        for (int k = 0; k < 128; ++k) s += fabsf(Aw[tid * 128 + k]);
        rs[tid]  = s;
        dwv[tid] = expf(dvec[tid]);
    }
    __syncthreads();
    #pragma unroll
    for (int half = 0; half < 2; ++half) {
        const int e    = blockIdx.x * 512 + half * 256 + tid;
        const int j    = e & 7;
        const int lane = (e >> 3) & 63;
        const int f    = e >> 9;          // 0..63
        const int nt   = f & 3;
        const int kt   = f >> 2;          // 0..15
        const int k    = kt * 16 + (lane >> 5) * 8 + j;
        const int n    = nt * 32 + (lane & 31);
        float v;
        if (k < 128) {
            v = Uw[n * 128 + k];
        } else {
            const int k2 = k - 128;
            v = Aw[n * 128 + k2] * (dwv[k2] / dwv[n]);
            if (n == k2) v += 0.05f - rs[n];
        }
        pre[e] = f2bf(v);
    }
}

// ---------------------------------------------------------------------------
// Main v12: nt-slab per wave, weights in REGISTERS, no LDS, no barriers.
// Block = 256 thr = 4 waves = 4 col-slabs of ONE 32-row tile (x/z shared
// via L1: 32 KB tile == L1 size). Per wave, straight-line: burst-issue
// W-slab (16 frags, 64 VGPR, L2-hot) + x (64 VGPR) + z (64 VGPR) ~= 12 KB
// in flight -- un-sinkable, this tile's MFMAs are the only downstream work.
// Then 16 MFMA (32x32x16) into a single 16-reg acc, 16 dense dword stores
// (each = 2 x 128 B segments; C layout m74/m101). Grid = 8192 one-tile
// blocks -> 4 backfill generations, desynchronized bursts.
// ---------------------------------------------------------------------------
__global__ __launch_bounds__(256, 1) void nemon_main(
    const float* __restrict__ x,
    const float* __restrict__ z,
    const float* __restrict__ Ub,
    const short* __restrict__ pre,
    float* __restrict__ out)
{
    const int tid  = threadIdx.x;
    const int wave = tid >> 6;            // nt-slab id 0..3
    const int lane = tid & 63;
    const int lo   = lane & 31;           // A row / C col (within slab)
    const int hi   = lane >> 5;           // k-half selector

    const long R = (long)blockIdx.x * 32; // this block's 32 rows

    // W-slab: frags f = kt*4 + wave, kt = 0..15  (64 VGPRs, L2-hot)
    bf8 w[16];
    #pragma unroll
    for (int kt = 0; kt < 16; ++kt)
        w[kt] = *(const bf8*)(pre + (long)((kt * 4 + wave) * 64 + lane) * 8);

    // x and z rows: 32 B/lane contiguous, fully coalesced; slab-mates hit L1
    const float* xr = x + (R + lo) * 128 + hi * 8;
    const float* zr = z + (R + lo) * 128 + hi * 8;
    f8 xv[8], zv[8];
    #pragma unroll
    for (int i = 0; i < 8; ++i) xv[i] = *(const f8*)(xr + i * 16);
    #pragma unroll
    for (int i = 0; i < 8; ++i) zv[i] = *(const f8*)(zr + i * 16);

    f32x16 acc;
    {
        const float b = Ub[wave * 32 + lo];
        #pragma unroll
        for (int r = 0; r < 16; ++r) acc[r] = b;
    }

    // x-half: k-steps 0..7 (xv[kt] covers k = kt*16 + hi*8 + j)
    #pragma unroll
    for (int kt = 0; kt < 8; ++kt) {
        union { bf8 b; unsigned u[4]; } a;
        a.u[0] = cvt_pk_bf16(xv[kt][0], xv[kt][1]);
        a.u[1] = cvt_pk_bf16(xv[kt][2], xv[kt][3]);
        a.u[2] = cvt_pk_bf16(xv[kt][4], xv[kt][5]);
        a.u[3] = cvt_pk_bf16(xv[kt][6], xv[kt][7]);
        acc = __builtin_amdgcn_mfma_f32_32x32x16_bf16(a.b, w[kt], acc, 0, 0, 0);
    }
    // z-half: k-steps 8..15
    #pragma unroll
    for (int kt = 0; kt < 8; ++kt) {
        union { bf8 b; unsigned u[4]; } a;
        a.u[0] = cvt_pk_bf16(zv[kt][0], zv[kt][1]);
        a.u[1] = cvt_pk_bf16(zv[kt][2], zv[kt][3]);
        a.u[2] = cvt_pk_bf16(zv[kt][4], zv[kt][5]);
        a.u[3] = cvt_pk_bf16(zv[kt][6], zv[kt][7]);
        acc = __builtin_amdgcn_mfma_f32_32x32x16_bf16(a.b, w[kt + 8], acc, 0, 0, 0);
    }

    // stores: C layout col = lane&31 (+slab offset), row = (reg&3)+8*(reg>>2)+4*hi
    float* ob = out + R * 128 + wave * 32 + lo;
    #pragma unroll
    for (int reg = 0; reg < 16; ++reg) {
        const int rowA = (reg & 3) + 8 * (reg >> 2) + 4 * hi;
        ob[rowA * 128] = acc[reg];
    }
}

extern "C" void kernel_launch(void* const* d_in, const int* in_sizes, int n_in,
                              void* d_out, int out_size, void* d_ws, size_t ws_size,
                              hipStream_t stream) {
    const float* x  = (const float*)d_in[0];
    const float* z  = (const float*)d_in[1];
    const float* Uw = (const float*)d_in[2];
    const float* Ub = (const float*)d_in[3];
    const float* Aw = (const float*)d_in[4];
    const float* dv = (const float*)d_in[5];
    float* out = (float*)d_out;
    short* pre = (short*)d_ws;            // 64 KB prepacked weights

    const int B = in_sizes[0] / 128;      // 262144 rows
    nemon_prep<<<64, 256, 0, stream>>>(Uw, Aw, dv, pre);
    nemon_main<<<B / 32, 256, 0, stream>>>(x, z, Ub, pre, out);
}

// Round 16
// 99.322 us; speedup vs baseline: 1.6200x; 1.6200x over previous
//
#include <hip/hip_runtime.h>
#include <hip/hip_bf16.h>

typedef __attribute__((ext_vector_type(4)))  float f4;
typedef __attribute__((ext_vector_type(16))) float f32x16;
typedef __attribute__((ext_vector_type(8)))  short bf8;

__device__ __forceinline__ short f2bf(float f) {
    unsigned u = __builtin_bit_cast(unsigned, f);
    u += 0x7fff + ((u >> 16) & 1);          // round-to-nearest-even
    return (short)(u >> 16);
}

__device__ __forceinline__ unsigned cvt_pk_bf16(float a, float b) {
    unsigned r;
    asm("v_cvt_pk_bf16_f32 %0, %1, %2" : "=v"(r) : "v"(a), "v"(b));
    return r;                                // lo = bf16(a), hi = bf16(b)
}

typedef __attribute__((address_space(1))) const void gas_void;
typedef __attribute__((address_space(3))) void       lds_void;

// async 16B/lane global->LDS DMA: per-lane global src, wave-uniform LDS base
__device__ __forceinline__ void gl_lds16(const float* g, const float* lds_base) {
    __builtin_amdgcn_global_load_lds((gas_void*)g, (lds_void*)lds_base, 16, 0, 0);
}

// ---------------------------------------------------------------------------
// Prep (validated rounds 7/11-15, absmax 0.5): fused B-matrix [256][128]
// packed as 32x32x16 MFMA B-fragments. f = kt*4+nt, kt=0..15, nt=0..3:
//   pre[(f*64 + lane)*8 + j] = Bmat[kt*16 + (lane>>5)*8 + j][nt*32 + (lane&31)]
//   Bmat[k][n] = k<128 ? U_w[n][k]
//                      : A_w[n][k-128]*dw[k-128]/dw[n] + (n==k-128)*(0.05-rs[n])
// ---------------------------------------------------------------------------
__global__ void nemon_prep(const float* __restrict__ Uw,
                           const float* __restrict__ Aw,
                           const float* __restrict__ dvec,
                           short* __restrict__ pre)
{
    __shared__ float rs[128], dwv[128];
    const int tid = threadIdx.x;
    if (tid < 128) {
        float s = 0.f;
        #pragma unroll 8
        for (int k = 0; k < 128; ++k) s += fabsf(Aw[tid * 128 + k]);
        rs[tid]  = s;
        dwv[tid] = expf(dvec[tid]);
    }
    __syncthreads();
    #pragma unroll
    for (int half = 0; half < 2; ++half) {
        const int e    = blockIdx.x * 512 + half * 256 + tid;
        const int j    = e & 7;
        const int lane = (e >> 3) & 63;
        const int f    = e >> 9;          // 0..63
        const int nt   = f & 3;
        const int kt   = f >> 2;          // 0..15
        const int k    = kt * 16 + (lane >> 5) * 8 + j;
        const int n    = nt * 32 + (lane & 31);
        float v;
        if (k < 128) {
            v = Uw[n * 128 + k];
        } else {
            const int k2 = k - 128;
            v = Aw[n * 128 + k2] * (dwv[k2] / dwv[n]);
            if (n == k2) v += 0.05f - rs[n];
        }
        pre[e] = f2bf(v);
    }
}

// ---------------------------------------------------------------------------
// Main v13: global_load_lds double-buffered staging (T3/T4 pattern).
// 256 thr = 4 waves (wave = nt-slab). LDS: W 64 KB + XZ dbuf 2 x 32 KB
// (x 16 KB | z 16 KB) = 128 KB, 1 block/CU. Per tile: issue 32 async DMA
// (8/wave) for tile t+1, counted vmcnt(24) (pops stage(t), leaves
// stage(t+1)+stores in flight -- NEVER drains to 0), raw s_barrier,
// ds_read swizzled A-frags + cvt_pk + 16 MFMA/wave, 16 dense dword stores,
// barrier. Staging uses ZERO registers -> compiler cannot sink/spill it.
// Source pre-swizzle c^=(row&7) (16B chunks) since gl_lds writes LDS
// linearly; ds_read applies the same XOR -> bank-conflict floor.
// ---------------------------------------------------------------------------
__global__ __launch_bounds__(256, 1) void nemon_main(
    const float* __restrict__ x,
    const float* __restrict__ z,
    const float* __restrict__ Ub,
    const short* __restrict__ pre,
    float* __restrict__ out)
{
    __shared__ short W[32768];            // 64 KB B-fragments
    __shared__ float XZ[2][8192];         // 2 x 32 KB: [0..4096)=x, [4096..8192)=z

    const int tid  = threadIdx.x;
    const int wave = tid >> 6;            // nt-slab id 0..3
    const int lane = tid & 63;
    const int lo   = lane & 31;           // A row / C col (within slab)
    const int hi   = lane >> 5;           // k-half selector

    const int  NT = 8;
    const long tile0 = (long)blockIdx.x * NT;

    // per-lane swizzled source offsets for this wave's 4 staging chunks
    // chunk g = wave*256 + i*64 + lane (16B units); row=g>>5, c=g&31
    int srcoff[4], ldsoff[4];
    #pragma unroll
    for (int i = 0; i < 4; ++i) {
        const int g   = wave * 256 + i * 64 + lane;
        const int row = g >> 5, c = g & 31;
        const int cs  = c ^ (row & 7);
        srcoff[i] = row * 128 + cs * 4;            // floats
        ldsoff[i] = (wave * 256 + i * 64) * 4;     // floats, wave-uniform
    }

    const float ub = Ub[wave * 32 + lo];

    // ---- prologue: stage tile0 (async), stage W (regular), full drain ----
    {
        const float* xt = x + tile0 * 32 * 128;
        const float* zt = z + tile0 * 32 * 128;
        #pragma unroll
        for (int i = 0; i < 4; ++i) {
            gl_lds16(xt + srcoff[i], &XZ[0][ldsoff[i]]);
            gl_lds16(zt + srcoff[i], &XZ[0][4096 + ldsoff[i]]);
        }
        const int4* src = (const int4*)pre;
        int4*       dst = (int4*)W;
        #pragma unroll
        for (int i = 0; i < 16; ++i) dst[tid + 256 * i] = src[tid + 256 * i];
    }
    __syncthreads();                      // drains DMA(t0) + W writes

    for (int t = 0; t < NT; ++t) {
        const int cur = t & 1;
        if (t < NT - 1) {                 // stage tile t+1 into other buffer
            const float* xt = x + (tile0 + t + 1) * 32 * 128;
            const float* zt = z + (tile0 + t + 1) * 32 * 128;
            #pragma unroll
            for (int i = 0; i < 4; ++i) {
                gl_lds16(xt + srcoff[i], &XZ[cur ^ 1][ldsoff[i]]);
                gl_lds16(zt + srcoff[i], &XZ[cur ^ 1][4096 + ldsoff[i]]);
            }
            // outstanding/wave: stage(t)8 + stores(t-1)16 + stage(t+1)8
            asm volatile("s_waitcnt vmcnt(24)" ::: "memory");
        } else {
            // outstanding/wave: stage(t)8 + stores(t-1)16
            asm volatile("s_waitcnt vmcnt(16)" ::: "memory");
        }
        __builtin_amdgcn_s_barrier();     // buf[cur] visible to all waves

        const float* bx = &XZ[cur][0];
        const float* bz = &XZ[cur][4096];

        f32x16 acc;
        #pragma unroll
        for (int r = 0; r < 16; ++r) acc[r] = ub;

        #pragma unroll
        for (int kt = 0; kt < 8; ++kt) {  // x-half: k-steps 0..7
            const int c0 = ((kt * 4 + hi * 2)     ^ (lo & 7)) * 4;
            const int c1 = ((kt * 4 + hi * 2 + 1) ^ (lo & 7)) * 4;
            f4 v0 = *(const f4*)&bx[lo * 128 + c0];
            f4 v1 = *(const f4*)&bx[lo * 128 + c1];
            union { bf8 b; unsigned u[4]; } a;
            a.u[0] = cvt_pk_bf16(v0[0], v0[1]);
            a.u[1] = cvt_pk_bf16(v0[2], v0[3]);
            a.u[2] = cvt_pk_bf16(v1[0], v1[1]);
            a.u[3] = cvt_pk_bf16(v1[2], v1[3]);
            bf8 w = *(const bf8*)&W[((kt * 4 + wave) * 64 + lane) * 8];
            acc = __builtin_amdgcn_mfma_f32_32x32x16_bf16(a.b, w, acc, 0, 0, 0);
        }
        #pragma unroll
        for (int kt = 0; kt < 8; ++kt) {  // z-half: k-steps 8..15
            const int c0 = ((kt * 4 + hi * 2)     ^ (lo & 7)) * 4;
            const int c1 = ((kt * 4 + hi * 2 + 1) ^ (lo & 7)) * 4;
            f4 v0 = *(const f4*)&bz[lo * 128 + c0];
            f4 v1 = *(const f4*)&bz[lo * 128 + c1];
            union { bf8 b; unsigned u[4]; } a;
            a.u[0] = cvt_pk_bf16(v0[0], v0[1]);
            a.u[1] = cvt_pk_bf16(v0[2], v0[3]);
            a.u[2] = cvt_pk_bf16(v1[0], v1[1]);
            a.u[3] = cvt_pk_bf16(v1[2], v1[3]);
            bf8 w = *(const bf8*)&W[(((kt + 8) * 4 + wave) * 64 + lane) * 8];
            acc = __builtin_amdgcn_mfma_f32_32x32x16_bf16(a.b, w, acc, 0, 0, 0);
        }

        // stores: C layout col = wave*32+lo, row = (reg&3)+8*(reg>>2)+4*hi
        float* ob = out + (tile0 + t) * 32 * 128 + wave * 32 + lo;
        #pragma unroll
        for (int reg = 0; reg < 16; ++reg) {
            const int rowA = (reg & 3) + 8 * (reg >> 2) + 4 * hi;
            ob[rowA * 128] = acc[reg];
        }

        __builtin_amdgcn_s_barrier();     // all reads of buf[cur] done
    }
}

extern "C" void kernel_launch(void* const* d_in, const int* in_sizes, int n_in,
                              void* d_out, int out_size, void* d_ws, size_t ws_size,
                              hipStream_t stream) {
    const float* x  = (const float*)d_in[0];
    const float* z  = (const float*)d_in[1];
    const float* Uw = (const float*)d_in[2];
    const float* Ub = (const float*)d_in[3];
    const float* Aw = (const float*)d_in[4];
    const float* dv = (const float*)d_in[5];
    float* out = (float*)d_out;
    short* pre = (short*)d_ws;            // 64 KB prepacked weights

    nemon_prep<<<64, 256, 0, stream>>>(Uw, Aw, dv, pre);
    nemon_main<<<1024, 256, 0, stream>>>(x, z, Ub, pre, out);
}